// Round 8
// baseline (394.551 us; speedup 1.0000x reference)
//
#include <hip/hip_runtime.h>
#include <hip/hip_bf16.h>
#include <stdint.h>

#define BROWS 16384
#define DIM   256
#define BM    256               // block rows (A panel)
#define BN    128               // block cols (B panel)
#define BKB   128               // K-tile in BYTES (fp8: 128 elems)
#define NBM   (BROWS / BM)      // 64 row blocks
#define NBN   (BROWS / BN)      // 128 col blocks
#define NCHUNK 256              // 64-wide column chunks per row

#define LOG2E 1.44269504088896340736f

typedef __attribute__((ext_vector_type(8))) int  i32x8;
typedef __attribute__((ext_vector_type(4))) float f32x4;
typedef unsigned char uchar;

__device__ __forceinline__ void gload_lds16(const void* g, void* l) {
  __builtin_amdgcn_global_load_lds(
      (const __attribute__((address_space(1))) void*)g,
      (__attribute__((address_space(3))) void*)l, 16, 0, 0);
}

// ---------------- Kernel A: normalize BOTH matrices + exact diag ------------
__global__ void normalize_both(const float* __restrict__ o,
                               const float* __restrict__ t,
                               uchar* __restrict__ o8,
                               uchar* __restrict__ t8,
                               float* __restrict__ dlog) {
  int row  = blockIdx.x * 4 + (threadIdx.x >> 6);
  int lane = threadIdx.x & 63;
  float4 a = *(reinterpret_cast<const float4*>(o + (size_t)row * DIM) + lane);
  float4 b = *(reinterpret_cast<const float4*>(t + (size_t)row * DIM) + lane);
  float sso = a.x * a.x + a.y * a.y + a.z * a.z + a.w * a.w;
  float sst = b.x * b.x + b.y * b.y + b.z * b.z + b.w * b.w;
  float d   = a.x * b.x + a.y * b.y + a.z * b.z + a.w * b.w;
#pragma unroll
  for (int m = 1; m < 64; m <<= 1) {
    sso += __shfl_xor(sso, m);
    sst += __shfl_xor(sst, m);
    d   += __shfl_xor(d, m);
  }
  float ro = rsqrtf(sso);
  float rt = rsqrtf(sst);
  if (lane == 0) dlog[row] = d * ro * rt;
  float qo = ro * LOG2E;
  int wo = 0, wt = 0;
  wo = __builtin_amdgcn_cvt_pk_fp8_f32(a.x * qo, a.y * qo, wo, false);
  wo = __builtin_amdgcn_cvt_pk_fp8_f32(a.z * qo, a.w * qo, wo, true);
  wt = __builtin_amdgcn_cvt_pk_fp8_f32(b.x * rt, b.y * rt, wt, false);
  wt = __builtin_amdgcn_cvt_pk_fp8_f32(b.z * rt, b.w * rt, wt, true);
  reinterpret_cast<int*>(o8 + (size_t)row * DIM)[lane] = wo;
  reinterpret_cast<int*>(t8 + (size_t)row * DIM)[lane] = wt;
}

// ---------------- Kernel B: fp8 GEMM (MX scale=1) + exp2 + partial sums -----
// 256x128 C-tile, 8 waves in 4x2 (wave tile 64x64 — identical per-thread code
// to the proven round-6 kernel), mfma_scale 16x16x128 fp8, identity scales.
// K=256 = 2 K-tiles, single-buffer 48 KiB LDS -> 3 blocks/CU (24 waves/CU).
// LDS dest linear (global_load_lds rule); global SOURCE carries the 32B-granule
// bank swizzle: LDS granule32 h of row r holds global granule32 h^(r&3).
// A/B frag (HW-verified r5/r6): lane l holds row (l&15), K-bytes [(l>>4)*32,+32)
// as one aligned i32x8. C/D: col = lane&15, row = (lane>>4)*4 + reg.
__global__ __launch_bounds__(512, 6) void gemm_expsum(
    const uchar* __restrict__ A8,   // ohat fp8, pre-scaled by log2e
    const uchar* __restrict__ B8,   // that fp8 (rows = logits cols)
    float* __restrict__ partial) {
  __shared__ __align__(32) uchar As[BM * BKB];  // 32 KB
  __shared__ __align__(32) uchar Bs[BN * BKB];  // 16 KB

  int tid  = threadIdx.x;
  int lane = tid & 63;
  int wid  = tid >> 6;
  int wr   = wid >> 1;      // wave row 0..3 (64-row strip of the 256)
  int wc   = wid & 1;       // wave col 0..1 (64-col strip of the 128)
  int bm   = blockIdx.x & (NBM - 1);
  int bn   = blockIdx.x >> 6;

  f32x4 acc[4][4];
#pragma unroll
  for (int m = 0; m < 4; ++m)
#pragma unroll
    for (int n = 0; n < 4; ++n) acc[m][n] = (f32x4){0.f, 0.f, 0.f, 0.f};

  const int srow = tid >> 3;   // 0..63: row within a 64-row staging pass
  const int sg   = tid & 7;    // 16B granule within the 128B row-chunk

  const uchar* gA = A8 + (size_t)bm * BM * DIM;
  const uchar* gB = B8 + (size_t)bn * BN * DIM;

  const int fr = lane & 15;
  const int kc = lane >> 4;    // 0..3: which 32-byte K-chunk this lane owns

#pragma unroll
  for (int kt = 0; kt < 2; ++kt) {
    // stage A (256 rows): 4 passes x (512 thr x 16B); B (128 rows): 2 passes
#pragma unroll
    for (int p = 0; p < 4; ++p) {
      int row  = p * 64 + srow;
      int g16  = ((((sg >> 1) ^ (row & 3)) << 1) | (sg & 1));
      gload_lds16(gA + (size_t)row * DIM + kt * BKB + (g16 << 4),
                  (char*)As + p * 8192 + wid * 1024);
    }
#pragma unroll
    for (int p = 0; p < 2; ++p) {
      int row  = p * 64 + srow;
      int g16  = ((((sg >> 1) ^ (row & 3)) << 1) | (sg & 1));
      gload_lds16(gB + (size_t)row * DIM + kt * BKB + (g16 << 4),
                  (char*)Bs + p * 8192 + wid * 1024);
    }
    __syncthreads();   // drains vmcnt(0): tile resident

    i32x8 bf[4];
#pragma unroll
    for (int n = 0; n < 4; ++n) {
      int row = wc * 64 + n * 16 + fr;
      bf[n] = *reinterpret_cast<const i32x8*>(Bs + row * BKB + ((kc ^ (row & 3)) << 5));
    }
#pragma unroll
    for (int m = 0; m < 4; ++m) {
      int row = wr * 64 + m * 16 + fr;
      i32x8 af = *reinterpret_cast<const i32x8*>(As + row * BKB + ((kc ^ (row & 3)) << 5));
#pragma unroll
      for (int n = 0; n < 4; ++n)
        acc[m][n] = __builtin_amdgcn_mfma_scale_f32_16x16x128_f8f6f4(
            af, bf[n], acc[m][n], 0, 0,               // cbsz=fp8, blgp=fp8
            0, 0x7F7F7F7F, 0, 0x7F7F7F7F);            // identity E8M0 scales
    }
    if (kt == 0) __syncthreads();   // readers done before next stage overwrites
  }

  // ---- epilogue: S = log2e * logit (bounded) -> v[j] = sum_n 2^S ----
  float v[16];
#pragma unroll
  for (int j = 0; j < 16; ++j) {
    int m = j >> 2, r = j & 3;
    v[j] = exp2f(acc[m][0][r]) + exp2f(acc[m][1][r]) +
           exp2f(acc[m][2][r]) + exp2f(acc[m][3][r]);
  }
  // butterfly-bisect over the 16 fragment columns: 15 shfl; lane ends with the
  // full column-sum for output row-index j = lane&15. (HW-verified r5/r6.)
#pragma unroll
  for (int s = 0; s < 4; ++s) {
    const int len = 16 >> s;
    const int bit = (lane >> s) & 1;
#pragma unroll
    for (int t = 0; t < 8; ++t) {
      if (t < (len >> 1)) {
        float a = v[2 * t], b = v[2 * t + 1];
        float recv = __shfl_xor(bit ? a : b, 1 << s);
        v[t] = (bit ? b : a) + recv;
      }
    }
  }
  {
    int j     = lane & 15;
    int sub   = lane >> 4;
    int row   = bm * BM + wr * 64 + (j >> 2) * 16 + sub * 4 + (j & 3);
    int chunk = (bn << 1) | wc;
    partial[(size_t)row * NCHUNK + chunk] = v[0];
  }
}

// ---------------- Kernel C: per-row finish: log(sum) - exact diag ----------
__global__ void row_finish(const float* __restrict__ partial,
                           const float* __restrict__ dlog,
                           float* __restrict__ rowloss) {
  int row  = blockIdx.x * 4 + (threadIdx.x >> 6);
  int lane = threadIdx.x & 63;
  float4 p = *(reinterpret_cast<const float4*>(partial + (size_t)row * NCHUNK) + lane);
  float s  = p.x + p.y + p.z + p.w;
#pragma unroll
  for (int m = 1; m < 64; m <<= 1) s += __shfl_xor(s, m);
  if (lane == 0) rowloss[row] = logf(s) - dlog[row];
}

// ---------------- Kernel D: mean over rows -> d_out[0] ----------------
__global__ void final_reduce(const float* __restrict__ rl, float* __restrict__ out) {
  __shared__ float sm[16];
  float s = 0.f;
  for (int i = threadIdx.x; i < BROWS; i += 1024) s += rl[i];
#pragma unroll
  for (int m = 1; m < 64; m <<= 1) s += __shfl_xor(s, m);
  int wid = threadIdx.x >> 6, lane = threadIdx.x & 63;
  if (lane == 0) sm[wid] = s;
  __syncthreads();
  if (wid == 0) {
    float v = (lane < 16) ? sm[lane] : 0.f;
#pragma unroll
    for (int m = 1; m < 16; m <<= 1) v += __shfl_xor(v, m);
    if (lane == 0) out[0] = v / (float)BROWS;
  }
}

extern "C" void kernel_launch(void* const* d_in, const int* in_sizes, int n_in,
                              void* d_out, int out_size, void* d_ws, size_t ws_size,
                              hipStream_t stream) {
  const float* outputs = (const float*)d_in[0];
  const float* targets = (const float*)d_in[1];
  float* out = (float*)d_out;
  char* ws = (char*)d_ws;

  uchar* o8      = (uchar*)ws;                                      // 4 MB
  uchar* t8      = (uchar*)(ws + (size_t)4 * 1024 * 1024);          // 4 MB
  float* partial = (float*)(ws + (size_t)8 * 1024 * 1024);          // 16 MB
  float* dlog    = (float*)(ws + (size_t)24 * 1024 * 1024);         // 64 KB
  float* rowloss = (float*)(ws + (size_t)24 * 1024 * 1024 + 65536); // 64 KB

  normalize_both<<<BROWS / 4, 256, 0, stream>>>(outputs, targets, o8, t8, dlog);
  gemm_expsum<<<NBM * NBN, 512, 0, stream>>>(o8, t8, partial);
  row_finish<<<BROWS / 4, 256, 0, stream>>>(partial, dlog, rowloss);
  final_reduce<<<1, 1024, 0, stream>>>(rowloss, out);
}

// Round 9
// 142.714 us; speedup vs baseline: 2.7646x; 2.7646x over previous
//
#include <hip/hip_runtime.h>
#include <hip/hip_bf16.h>
#include <stdint.h>

#define BROWS 16384
#define DIM   256
#define BM    128
#define BN    128
#define NBM   (BROWS / BM)      // 128 row blocks
#define NCHUNK 256              // 64-wide column chunks per row

#define LOG2E 1.44269504088896340736f

typedef __attribute__((ext_vector_type(8)))  int   i32x8;
typedef __attribute__((ext_vector_type(16))) float f32x16;
typedef unsigned char uchar;

__device__ __forceinline__ void gload_lds16(const void* g, void* l) {
  __builtin_amdgcn_global_load_lds(
      (const __attribute__((address_space(1))) void*)g,
      (__attribute__((address_space(3))) void*)l, 16, 0, 0);
}

// ---------------- Kernel A: normalize BOTH matrices + exact diag ------------
__global__ void normalize_both(const float* __restrict__ o,
                               const float* __restrict__ t,
                               uchar* __restrict__ o8,
                               uchar* __restrict__ t8,
                               float* __restrict__ dlog) {
  int row  = blockIdx.x * 4 + (threadIdx.x >> 6);
  int lane = threadIdx.x & 63;
  float4 a = *(reinterpret_cast<const float4*>(o + (size_t)row * DIM) + lane);
  float4 b = *(reinterpret_cast<const float4*>(t + (size_t)row * DIM) + lane);
  float sso = a.x * a.x + a.y * a.y + a.z * a.z + a.w * a.w;
  float sst = b.x * b.x + b.y * b.y + b.z * b.z + b.w * b.w;
  float d   = a.x * b.x + a.y * b.y + a.z * b.z + a.w * b.w;
#pragma unroll
  for (int m = 1; m < 64; m <<= 1) {
    sso += __shfl_xor(sso, m);
    sst += __shfl_xor(sst, m);
    d   += __shfl_xor(d, m);
  }
  float ro = rsqrtf(sso);
  float rt = rsqrtf(sst);
  if (lane == 0) dlog[row] = d * ro * rt;
  float qo = ro * LOG2E;
  int wo = 0, wt = 0;
  wo = __builtin_amdgcn_cvt_pk_fp8_f32(a.x * qo, a.y * qo, wo, false);
  wo = __builtin_amdgcn_cvt_pk_fp8_f32(a.z * qo, a.w * qo, wo, true);
  wt = __builtin_amdgcn_cvt_pk_fp8_f32(b.x * rt, b.y * rt, wt, false);
  wt = __builtin_amdgcn_cvt_pk_fp8_f32(b.z * rt, b.w * rt, wt, true);
  reinterpret_cast<int*>(o8 + (size_t)row * DIM)[lane] = wo;
  reinterpret_cast<int*>(t8 + (size_t)row * DIM)[lane] = wt;
}

// Swizzled fragment read for mfma_scale_f32_32x32x64_f8f6f4:
// lane holds row (lane&31) of the 32-row frag, K-bytes [p*32, p*32+32) where
// p = k*2 + (lane>>5). LDS 16B-granule h of row r holds GLOBAL granule
// h^(r&7) (involution; applied on the staging source side). The two 16B
// halves of the wanted 32B chunk live at byte offsets h0*16 and (h0*16)^16.
__device__ __forceinline__ i32x8 ldsfrag(const uchar* mat, int row, int p) {
  const uchar* rb = mat + row * DIM;
  int h0 = (((p << 1) ^ (row & 7)) << 4);
  const int4 lo = *reinterpret_cast<const int4*>(rb + h0);          // K-lo 16B
  const int4 hi = *reinterpret_cast<const int4*>(rb + (h0 ^ 16));   // K-hi 16B
  return (i32x8){lo.x, lo.y, lo.z, lo.w, hi.x, hi.y, hi.z, hi.w};
}

// ---------------- Kernel B: fp8 GEMM (MX scale=1) + exp2 + partial sums -----
// 128x128 C-tile, 4 waves 2x2 (wave tile 64x64), mfma_scale 32x32x64 fp8,
// identity E8M0 scales. FULL K=256 staged once (As/Bs 32 KB each, 64 KB LDS)
// -> ONE barrier total, no mid-kernel vmcnt(0) drains. 16B-granule XOR row
// swizzle (source-side) -> conflict-free ds_read_b128 pairs.
// C/D (shape-determined, m74/m101/m121-128): col = lane&31,
// row = (reg&3) + 8*(reg>>2) + 4*(lane>>5).
__global__ __launch_bounds__(256, 2) void gemm_expsum(
    const uchar* __restrict__ A8,   // ohat fp8, pre-scaled by log2e
    const uchar* __restrict__ B8,   // that fp8 (rows = logits cols)
    float* __restrict__ partial) {
  __shared__ __align__(16) uchar As[BM * DIM];  // 32 KB
  __shared__ __align__(16) uchar Bs[BN * DIM];  // 32 KB

  int tid  = threadIdx.x;
  int lane = tid & 63;
  int wid  = tid >> 6;
  int wr   = wid >> 1;      // wave row 0..1
  int wc   = wid & 1;       // wave col 0..1
  int bm   = blockIdx.x & (NBM - 1);
  int bn   = blockIdx.x >> 7;

  const uchar* gA = A8 + (size_t)bm * BM * DIM;
  const uchar* gB = B8 + (size_t)bn * BN * DIM;

  // stage full panels: 8 passes x (256 thr x 16B) = 16 rows/pass, per matrix.
  // LDS dest linear (global_load_lds rule); source granule carries the swizzle.
  const int srow = tid >> 4;   // 0..15
  const int sh   = tid & 15;   // 16B granule within the 256B row
#pragma unroll
  for (int p = 0; p < 8; ++p) {
    int row  = p * 16 + srow;
    int goff = (sh ^ (row & 7)) << 4;
    gload_lds16(gA + (size_t)row * DIM + goff, (char*)As + p * 4096 + wid * 1024);
  }
#pragma unroll
  for (int p = 0; p < 8; ++p) {
    int row  = p * 16 + srow;
    int goff = (sh ^ (row & 7)) << 4;
    gload_lds16(gB + (size_t)row * DIM + goff, (char*)Bs + p * 4096 + wid * 1024);
  }
  __syncthreads();   // the ONLY barrier: drains vmcnt(0), panels resident

  const int col = lane & 31;
  const int hi  = lane >> 5;

  f32x16 acc[2][2];
#pragma unroll
  for (int m = 0; m < 2; ++m)
#pragma unroll
    for (int n = 0; n < 2; ++n)
#pragma unroll
      for (int r = 0; r < 16; ++r) acc[m][n][r] = 0.f;

#pragma unroll
  for (int k = 0; k < 4; ++k) {      // K = 256 fp8 = 4 steps of 64
    const int p = k * 2 + hi;        // lane's 32B granule index
    i32x8 af[2], bf[2];
#pragma unroll
    for (int m = 0; m < 2; ++m) af[m] = ldsfrag(As, wr * 64 + m * 32 + col, p);
#pragma unroll
    for (int n = 0; n < 2; ++n) bf[n] = ldsfrag(Bs, wc * 64 + n * 32 + col, p);
#pragma unroll
    for (int m = 0; m < 2; ++m)
#pragma unroll
      for (int n = 0; n < 2; ++n)
        acc[m][n] = __builtin_amdgcn_mfma_scale_f32_32x32x64_f8f6f4(
            af[m], bf[n], acc[m][n], 0, 0,            // cbsz=fp8, blgp=fp8
            0, 0x7F7F7F7F, 0, 0x7F7F7F7F);            // identity E8M0 scales
  }

  // ---- epilogue: S = log2e * logit (bounded) -> v[j] = sum_n 2^S ----
  // j = mm*16 + rr indexes the lane's 32 output rows (at its col).
  float v[32];
#pragma unroll
  for (int j = 0; j < 32; ++j) {
    int mm = j >> 4, rr = j & 15;
    v[j] = exp2f(acc[mm][0][rr]) + exp2f(acc[mm][1][rr]);
  }
  // 5-stage bisect butterfly over the 32 cols (lanes within each 32-half):
  // lane ends with the full col-sum for j = lane&31.
#pragma unroll
  for (int s = 0; s < 5; ++s) {
    const int len = 32 >> s;
    const int bit = (lane >> s) & 1;
#pragma unroll
    for (int t = 0; t < 16; ++t) {
      if (t < (len >> 1)) {
        float a = v[2 * t], b = v[2 * t + 1];
        float recv = __shfl_xor(bit ? a : b, 1 << s);
        v[t] = (bit ? b : a) + recv;
      }
    }
  }
  {
    int j   = lane & 31;
    int mm  = j >> 4, rr = j & 15;
    int row = bm * BM + wr * 64 + mm * 32 + (rr & 3) + 8 * (rr >> 2) + 4 * hi;
    int chunk = (bn << 1) | wc;
    partial[(size_t)row * NCHUNK + chunk] = v[0];
  }
}

// ---------------- Kernel C: per-row finish: log(sum) - exact diag ----------
__global__ void row_finish(const float* __restrict__ partial,
                           const float* __restrict__ dlog,
                           float* __restrict__ rowloss) {
  int row  = blockIdx.x * 4 + (threadIdx.x >> 6);
  int lane = threadIdx.x & 63;
  float4 p = *(reinterpret_cast<const float4*>(partial + (size_t)row * NCHUNK) + lane);
  float s  = p.x + p.y + p.z + p.w;
#pragma unroll
  for (int m = 1; m < 64; m <<= 1) s += __shfl_xor(s, m);
  if (lane == 0) rowloss[row] = logf(s) - dlog[row];
}

// ---------------- Kernel D: mean over rows -> d_out[0] ----------------
__global__ void final_reduce(const float* __restrict__ rl, float* __restrict__ out) {
  __shared__ float sm[16];
  float s = 0.f;
  for (int i = threadIdx.x; i < BROWS; i += 1024) s += rl[i];
#pragma unroll
  for (int m = 1; m < 64; m <<= 1) s += __shfl_xor(s, m);
  int wid = threadIdx.x >> 6, lane = threadIdx.x & 63;
  if (lane == 0) sm[wid] = s;
  __syncthreads();
  if (wid == 0) {
    float v = (lane < 16) ? sm[lane] : 0.f;
#pragma unroll
    for (int m = 1; m < 16; m <<= 1) v += __shfl_xor(v, m);
    if (lane == 0) out[0] = v / (float)BROWS;
  }
}

extern "C" void kernel_launch(void* const* d_in, const int* in_sizes, int n_in,
                              void* d_out, int out_size, void* d_ws, size_t ws_size,
                              hipStream_t stream) {
  const float* outputs = (const float*)d_in[0];
  const float* targets = (const float*)d_in[1];
  float* out = (float*)d_out;
  char* ws = (char*)d_ws;

  uchar* o8      = (uchar*)ws;                                      // 4 MB
  uchar* t8      = (uchar*)(ws + (size_t)4 * 1024 * 1024);          // 4 MB
  float* partial = (float*)(ws + (size_t)8 * 1024 * 1024);          // 16 MB
  float* dlog    = (float*)(ws + (size_t)24 * 1024 * 1024);         // 64 KB
  float* rowloss = (float*)(ws + (size_t)24 * 1024 * 1024 + 65536); // 64 KB

  normalize_both<<<BROWS / 4, 256, 0, stream>>>(outputs, targets, o8, t8, dlog);
  gemm_expsum<<<NBM * (BROWS / BN), 256, 0, stream>>>(o8, t8, partial);
  row_finish<<<BROWS / 4, 256, 0, stream>>>(partial, dlog, rowloss);
  final_reduce<<<1, 1024, 0, stream>>>(rowloss, out);
}